// Round 1
// baseline (333.087 us; speedup 1.0000x reference)
//
#include <hip/hip_runtime.h>
#include <hip/hip_bf16.h>

// GRU: B=4096, T=512, I=1, H=32, C=2.
// One 32-lane group per batch element; lane j owns h[j] and W_hh rows
// {j, 32+j, 64+j} in registers. h[k] broadcast via ds_swizzle (imm k<<5).
// Grid 512x256 = 2048 waves = 2 waves/SIMD across 256 CUs.

#define BCASTF(v, k) \
    __uint_as_float((unsigned)__builtin_amdgcn_ds_swizzle((int)__float_as_uint(v), ((k) << 5)))

#define KSTEP(k)                                    \
    {                                               \
        float hk = BCASTF(h, k);                    \
        ar = fmaf(hk, Wr[k], ar);                   \
        az = fmaf(hk, Wz[k], az);                   \
        an = fmaf(hk, Wn[k], an);                   \
    }

__global__ __launch_bounds__(256, 2)
void gru_fused_kernel(const float* __restrict__ x,
                      const float* __restrict__ W_ih,
                      const float* __restrict__ W_hh,
                      const float* __restrict__ b_ih,
                      const float* __restrict__ b_hh,
                      const float* __restrict__ fc_w,
                      const float* __restrict__ fc_b,
                      float* __restrict__ out)
{
    const int tid = threadIdx.x;
    const int j   = tid & 31;               // hidden index this lane owns
    const int bb  = blockIdx.x * 8 + (tid >> 5);  // batch element (8 per block)

    // ---- per-lane weights in registers (96 VGPRs) ----
    float Wr[32], Wz[32], Wn[32];
    {
        const float4* wr4 = reinterpret_cast<const float4*>(W_hh + (j) * 32);
        const float4* wz4 = reinterpret_cast<const float4*>(W_hh + (32 + j) * 32);
        const float4* wn4 = reinterpret_cast<const float4*>(W_hh + (64 + j) * 32);
        #pragma unroll
        for (int q = 0; q < 8; ++q) {
            float4 a = wr4[q], b = wz4[q], c = wn4[q];
            Wr[4*q+0] = a.x; Wr[4*q+1] = a.y; Wr[4*q+2] = a.z; Wr[4*q+3] = a.w;
            Wz[4*q+0] = b.x; Wz[4*q+1] = b.y; Wz[4*q+2] = b.z; Wz[4*q+3] = b.w;
            Wn[4*q+0] = c.x; Wn[4*q+1] = c.y; Wn[4*q+2] = c.z; Wn[4*q+3] = c.w;
        }
    }

    // biases / input weights (I == 1)
    const float br   = b_ih[j]      + b_hh[j];        // r-gate combined bias
    const float bz   = b_ih[32 + j] + b_hh[32 + j];   // z-gate combined bias
    const float bin  = b_ih[64 + j];                  // n-gate input-side bias
    const float bhn  = b_hh[64 + j];                  // n-gate hidden-side bias
    const float wihr = W_ih[j];
    const float wihz = W_ih[32 + j];
    const float wihn = W_ih[64 + j];

    const float* xp = x + (size_t)bb * 512;
    float h = 0.0f;

    // chunk 0 of x: lane j holds x[bb, j]
    float xcur = xp[j];

    for (int c = 0; c < 16; ++c) {
        // prefetch next chunk (wraps at c=15; value unused)
        float xnext = xp[((c + 1) & 15) * 32 + j];

        #pragma unroll 2
        for (int tt = 0; tt < 32; ++tt) {
            float xb = __shfl(xcur, tt, 32);   // x[bb, 32*c + tt]

            float ar = br, az = bz, an = bhn;
            KSTEP(0)  KSTEP(1)  KSTEP(2)  KSTEP(3)
            KSTEP(4)  KSTEP(5)  KSTEP(6)  KSTEP(7)
            KSTEP(8)  KSTEP(9)  KSTEP(10) KSTEP(11)
            KSTEP(12) KSTEP(13) KSTEP(14) KSTEP(15)
            KSTEP(16) KSTEP(17) KSTEP(18) KSTEP(19)
            KSTEP(20) KSTEP(21) KSTEP(22) KSTEP(23)
            KSTEP(24) KSTEP(25) KSTEP(26) KSTEP(27)
            KSTEP(28) KSTEP(29) KSTEP(30) KSTEP(31)

            ar = fmaf(xb, wihr, ar);
            az = fmaf(xb, wihz, az);

            float r = 1.0f / (1.0f + __expf(-ar));
            float z = 1.0f / (1.0f + __expf(-az));

            float npre = fmaf(r, an, fmaf(xb, wihn, bin));
            // tanh(a) = 1 - 2/(1 + exp(2a)); saturates correctly at +/-inf
            float n = 1.0f - 2.0f / (1.0f + __expf(2.0f * npre));

            h = n + z * (h - n);
        }
        xcur = xnext;
    }

    // ---- FC epilogue: out[bb, c] = sum_j h_j * fc_w[c*32+j] + fc_b[c] ----
    float s0 = h * fc_w[j];
    float s1 = h * fc_w[32 + j];
    #pragma unroll
    for (int off = 16; off >= 1; off >>= 1) {
        s0 += __shfl_xor(s0, off, 32);
        s1 += __shfl_xor(s1, off, 32);
    }
    if (j == 0) {
        out[(size_t)bb * 2 + 0] = s0 + fc_b[0];
        out[(size_t)bb * 2 + 1] = s1 + fc_b[1];
    }
}

extern "C" void kernel_launch(void* const* d_in, const int* in_sizes, int n_in,
                              void* d_out, int out_size, void* d_ws, size_t ws_size,
                              hipStream_t stream)
{
    const float* x    = (const float*)d_in[0];
    const float* W_ih = (const float*)d_in[1];
    const float* W_hh = (const float*)d_in[2];
    const float* b_ih = (const float*)d_in[3];
    const float* b_hh = (const float*)d_in[4];
    const float* fc_w = (const float*)d_in[5];
    const float* fc_b = (const float*)d_in[6];
    float* out = (float*)d_out;

    // B=4096 batches, 8 per block (256 threads = 8 x 32-lane groups)
    dim3 grid(512), block(256);
    hipLaunchKernelGGL(gru_fused_kernel, grid, block, 0, stream,
                       x, W_ih, W_hh, b_ih, b_hh, fc_w, fc_b, out);
}

// Round 3
// 246.748 us; speedup vs baseline: 1.3499x; 1.3499x over previous
//
#include <hip/hip_runtime.h>
#include <hip/hip_bf16.h>

// GRU: B=4096, T=512, I=1, H=32, C=2.
// One 32-lane group per batch element. Every lane holds the FULL h vector
// replicated as 16 packed fp16x2 regs; lane j owns W_hh rows {j,32+j,64+j}
// packed fp16x2 (48 VGPRs). Per step: 48 v_dot2_f32_f16 + gate math,
// then h re-replication via 1 xor-swizzle + cvt_pkrtz + 16 bcast swizzles.
// Grid 512x256 = 2048 waves = 2 waves/SIMD on 256 CUs.

typedef _Float16 half2v __attribute__((ext_vector_type(2)));
using pk16 = decltype(__builtin_amdgcn_cvt_pkrtz(0.0f, 0.0f));  // __fp16 x2

__device__ __forceinline__ float fdot2f(pk16 a, pk16 b, float c) {
#if __has_builtin(__builtin_amdgcn_fdot2)
    return __builtin_amdgcn_fdot2(__builtin_bit_cast(half2v, a),
                                  __builtin_bit_cast(half2v, b), c, false);
#else
    return c + (float)a[0] * (float)b[0] + (float)a[1] * (float)b[1];
#endif
}

// broadcast packed pair p (held in even lane 2p) to all 32 lanes of the group
#define HBCAST(p) \
    hh[p] = __builtin_bit_cast(pk16, __builtin_amdgcn_ds_swizzle(opu, ((2 * (p)) << 5)))

__global__ __launch_bounds__(256, 2)
void gru_fused_kernel(const float* __restrict__ x,
                      const float* __restrict__ W_ih,
                      const float* __restrict__ W_hh,
                      const float* __restrict__ b_ih,
                      const float* __restrict__ b_hh,
                      const float* __restrict__ fc_w,
                      const float* __restrict__ fc_b,
                      float* __restrict__ out)
{
    const int tid = threadIdx.x;
    const int j   = tid & 31;                      // hidden index this lane owns
    const int bb  = blockIdx.x * 8 + (tid >> 5);   // batch element (8 per block)

    // ---- per-lane weight rows, packed fp16x2 (48 VGPRs) ----
    pk16 wr[16], wz[16], wn[16];
    {
        const float4* wr4 = reinterpret_cast<const float4*>(W_hh + (j) * 32);
        const float4* wz4 = reinterpret_cast<const float4*>(W_hh + (32 + j) * 32);
        const float4* wn4 = reinterpret_cast<const float4*>(W_hh + (64 + j) * 32);
        #pragma unroll
        for (int q = 0; q < 8; ++q) {
            float4 a = wr4[q], b = wz4[q], c = wn4[q];
            wr[2*q]   = __builtin_amdgcn_cvt_pkrtz(a.x, a.y);
            wr[2*q+1] = __builtin_amdgcn_cvt_pkrtz(a.z, a.w);
            wz[2*q]   = __builtin_amdgcn_cvt_pkrtz(b.x, b.y);
            wz[2*q+1] = __builtin_amdgcn_cvt_pkrtz(b.z, b.w);
            wn[2*q]   = __builtin_amdgcn_cvt_pkrtz(c.x, c.y);
            wn[2*q+1] = __builtin_amdgcn_cvt_pkrtz(c.z, c.w);
        }
    }

    // biases / input weights (I == 1)
    const float br   = b_ih[j]      + b_hh[j];
    const float bz   = b_ih[32 + j] + b_hh[32 + j];
    const float bin  = b_ih[64 + j];
    const float bhn  = b_hh[64 + j];
    const float wihr = W_ih[j];
    const float wihz = W_ih[32 + j];
    const float wihn = W_ih[64 + j];

    const float* xp = x + (size_t)bb * 512;
    float h = 0.0f;                     // own h[j], fp32

    pk16 hh[16];                        // full h vector, replicated, packed
    #pragma unroll
    for (int p = 0; p < 16; ++p) hh[p] = __builtin_amdgcn_cvt_pkrtz(0.0f, 0.0f);

    float xcur = xp[j];                 // chunk 0 of x

    for (int c = 0; c < 16; ++c) {
        float xnext = xp[((c + 1) & 15) * 32 + j];   // prefetch next chunk

        #pragma unroll 2
        for (int tt = 0; tt < 32; ++tt) {
            float xb = __shfl(xcur, tt, 32);         // x[bb, 32*c + tt]

            float ar = fmaf(xb, wihr, br);
            float az = fmaf(xb, wihz, bz);
            float an = bhn;
            #pragma unroll
            for (int p = 0; p < 16; ++p) {
                ar = fdot2f(wr[p], hh[p], ar);
                az = fdot2f(wz[p], hh[p], az);
                an = fdot2f(wn[p], hh[p], an);
            }

            float r = 1.0f / (1.0f + __expf(-ar));
            float z = 1.0f / (1.0f + __expf(-az));
            float npre = fmaf(r, an, fmaf(xb, wihn, bin));
            float n = 1.0f - 2.0f / (1.0f + __expf(2.0f * npre));
            h = fmaf(z, h - n, n);       // h = n + z*(h-n)

            // ---- re-replicate h to all lanes as packed fp16 pairs ----
            int nb = __builtin_amdgcn_ds_swizzle(__float_as_int(h), 0x041F); // xor 1
            pk16 pk = __builtin_amdgcn_cvt_pkrtz(h, __int_as_float(nb));
            // even lane 2p now holds {h[2p], h[2p+1]}; odd lanes' pk unused
            int opu = __builtin_bit_cast(int, pk);
            HBCAST(0);  HBCAST(1);  HBCAST(2);  HBCAST(3);
            HBCAST(4);  HBCAST(5);  HBCAST(6);  HBCAST(7);
            HBCAST(8);  HBCAST(9);  HBCAST(10); HBCAST(11);
            HBCAST(12); HBCAST(13); HBCAST(14); HBCAST(15);
        }
        xcur = xnext;
    }

    // ---- FC epilogue: out[bb, c] = sum_j h_j * fc_w[c*32+j] + fc_b[c] ----
    float s0 = h * fc_w[j];
    float s1 = h * fc_w[32 + j];
    #pragma unroll
    for (int off = 16; off >= 1; off >>= 1) {
        s0 += __shfl_xor(s0, off, 32);
        s1 += __shfl_xor(s1, off, 32);
    }
    if (j == 0) {
        out[(size_t)bb * 2 + 0] = s0 + fc_b[0];
        out[(size_t)bb * 2 + 1] = s1 + fc_b[1];
    }
}

extern "C" void kernel_launch(void* const* d_in, const int* in_sizes, int n_in,
                              void* d_out, int out_size, void* d_ws, size_t ws_size,
                              hipStream_t stream)
{
    const float* x    = (const float*)d_in[0];
    const float* W_ih = (const float*)d_in[1];
    const float* W_hh = (const float*)d_in[2];
    const float* b_ih = (const float*)d_in[3];
    const float* b_hh = (const float*)d_in[4];
    const float* fc_w = (const float*)d_in[5];
    const float* fc_b = (const float*)d_in[6];
    float* out = (float*)d_out;

    dim3 grid(512), block(256);
    hipLaunchKernelGGL(gru_fused_kernel, grid, block, 0, stream,
                       x, W_ih, W_hh, b_ih, b_hh, fc_w, fc_b, out);
}

// Round 5
// 244.414 us; speedup vs baseline: 1.3628x; 1.0095x over previous
//
#include <hip/hip_runtime.h>
#include <hip/hip_bf16.h>

// GRU: B=4096, T=512, I=1, H=32, C=2.
// One 32-lane group per batch element. Every lane holds the FULL h vector
// replicated as 16 packed fp16x2 NAMED regs; lane j owns W_hh rows
// {j,32+j,64+j} as 48 NAMED packed regs (no arrays -> no scratch/AGPR demotion).
// Per step: 48 v_dot2_f32_f16 + gate math, then h re-replication via
// 1 xor-swizzle + cvt_pkrtz + 16 bcast swizzles.
// Grid 512x256 = 2048 waves = 2 waves/SIMD on 256 CUs.

typedef _Float16 half2v __attribute__((ext_vector_type(2)));
using pk16 = decltype(__builtin_amdgcn_cvt_pkrtz(0.0f, 0.0f));  // __fp16 x2

__device__ __forceinline__ float fdot2f(pk16 a, pk16 b, float c) {
    return __builtin_amdgcn_fdot2(__builtin_bit_cast(half2v, a),
                                  __builtin_bit_cast(half2v, b), c, false);
}

#define FOR16(M) M(0) M(1) M(2) M(3) M(4) M(5) M(6) M(7) \
                 M(8) M(9) M(10) M(11) M(12) M(13) M(14) M(15)

__global__ __launch_bounds__(256, 2)
void gru_fused_kernel(const float* __restrict__ x,
                      const float* __restrict__ W_ih,
                      const float* __restrict__ W_hh,
                      const float* __restrict__ b_ih,
                      const float* __restrict__ b_hh,
                      const float* __restrict__ fc_w,
                      const float* __restrict__ fc_b,
                      float* __restrict__ out)
{
    const int tid = threadIdx.x;
    const int j   = tid & 31;                      // hidden index this lane owns
    const int bb  = blockIdx.x * 8 + (tid >> 5);   // batch element (8 per block)

    // ---- named packed weight registers (48 VGPRs) + replicated h (16) ----
#define DECLP(p) pk16 wr##p, wz##p, wn##p, hh##p;
    FOR16(DECLP)
#undef DECLP

    {
        const float4* wrp = reinterpret_cast<const float4*>(W_hh + (j) * 32);
        const float4* wzp = reinterpret_cast<const float4*>(W_hh + (32 + j) * 32);
        const float4* wnp = reinterpret_cast<const float4*>(W_hh + (64 + j) * 32);
#define INITQ(q, p0, p1)                                        \
        {                                                       \
            float4 a = wrp[q], b = wzp[q], c = wnp[q];          \
            wr##p0 = __builtin_amdgcn_cvt_pkrtz(a.x, a.y);      \
            wr##p1 = __builtin_amdgcn_cvt_pkrtz(a.z, a.w);      \
            wz##p0 = __builtin_amdgcn_cvt_pkrtz(b.x, b.y);      \
            wz##p1 = __builtin_amdgcn_cvt_pkrtz(b.z, b.w);      \
            wn##p0 = __builtin_amdgcn_cvt_pkrtz(c.x, c.y);      \
            wn##p1 = __builtin_amdgcn_cvt_pkrtz(c.z, c.w);      \
        }
        INITQ(0, 0, 1)  INITQ(1, 2, 3)  INITQ(2, 4, 5)  INITQ(3, 6, 7)
        INITQ(4, 8, 9)  INITQ(5, 10, 11) INITQ(6, 12, 13) INITQ(7, 14, 15)
#undef INITQ
    }

    // biases / input weights (I == 1)
    const float br   = b_ih[j]      + b_hh[j];
    const float bz   = b_ih[32 + j] + b_hh[32 + j];
    const float bin  = b_ih[64 + j];
    const float bhn  = b_hh[64 + j];
    const float wihr = W_ih[j];
    const float wihz = W_ih[32 + j];
    const float wihn = W_ih[64 + j];

    const float* xp = x + (size_t)bb * 512;
    float h = 0.0f;                     // own h[j], fp32

#define ZEROH(p) hh##p = __builtin_amdgcn_cvt_pkrtz(0.0f, 0.0f);
    FOR16(ZEROH)
#undef ZEROH

    float xcur = xp[j];                 // chunk 0 of x

    for (int c = 0; c < 16; ++c) {
        float xnext = xp[((c + 1) & 15) * 32 + j];   // prefetch next chunk

        #pragma unroll 2
        for (int tt = 0; tt < 32; ++tt) {
            float xb = __shfl(xcur, tt, 32);         // x[bb, 32*c + tt]

            float ar = fmaf(xb, wihr, br);
            float az = fmaf(xb, wihz, bz);
            float an = bhn;
#define DOT(p)                                  \
            ar = fdot2f(wr##p, hh##p, ar);      \
            az = fdot2f(wz##p, hh##p, az);      \
            an = fdot2f(wn##p, hh##p, an);
            FOR16(DOT)
#undef DOT

            float r = 1.0f / (1.0f + __expf(-ar));
            float z = 1.0f / (1.0f + __expf(-az));
            float npre = fmaf(r, an, fmaf(xb, wihn, bin));
            float n = 1.0f - 2.0f / (1.0f + __expf(2.0f * npre));
            h = fmaf(z, h - n, n);       // h = n + z*(h-n)

            // ---- re-replicate h to all lanes as packed fp16 pairs ----
            int nb = __builtin_amdgcn_ds_swizzle(__float_as_int(h), 0x041F); // xor 1
            pk16 pk = __builtin_amdgcn_cvt_pkrtz(h, __int_as_float(nb));
            // even lane 2p holds {h[2p], h[2p+1]}; odd lanes' pk never read
            int opu = __builtin_bit_cast(int, pk);
#define HB(p) hh##p = __builtin_bit_cast(pk16, \
                  __builtin_amdgcn_ds_swizzle(opu, ((2 * (p)) << 5)));
            FOR16(HB)
#undef HB
        }
        xcur = xnext;
    }

    // ---- FC epilogue: out[bb, c] = sum_j h_j * fc_w[c*32+j] + fc_b[c] ----
    float s0 = h * fc_w[j];
    float s1 = h * fc_w[32 + j];
    #pragma unroll
    for (int off = 16; off >= 1; off >>= 1) {
        s0 += __shfl_xor(s0, off, 32);
        s1 += __shfl_xor(s1, off, 32);
    }
    if (j == 0) {
        out[(size_t)bb * 2 + 0] = s0 + fc_b[0];
        out[(size_t)bb * 2 + 1] = s1 + fc_b[1];
    }
}

extern "C" void kernel_launch(void* const* d_in, const int* in_sizes, int n_in,
                              void* d_out, int out_size, void* d_ws, size_t ws_size,
                              hipStream_t stream)
{
    const float* x    = (const float*)d_in[0];
    const float* W_ih = (const float*)d_in[1];
    const float* W_hh = (const float*)d_in[2];
    const float* b_ih = (const float*)d_in[3];
    const float* b_hh = (const float*)d_in[4];
    const float* fc_w = (const float*)d_in[5];
    const float* fc_b = (const float*)d_in[6];
    float* out = (float*)d_out;

    dim3 grid(512), block(256);
    hipLaunchKernelGGL(gru_fused_kernel, grid, block, 0, stream,
                       x, W_ih, W_hh, b_ih, b_hh, fc_w, fc_b, out);
}